// Round 5
// baseline (281.735 us; speedup 1.0000x reference)
//
#include <hip/hip_runtime.h>
#include <hip/hip_bf16.h>
#include <math.h>

#define BB 4
#define NN 3000
#define NR 3008         // apk padded rows (NIT*16)
#define NC 3072         // apk padded cols (NKC*32)
#define FF 128
#define NKC 96          // 32-wide K chunks (96*32 = 3072)
#define NIT 188         // 16-row tiles (188*16 = 3008)
#define TS  536         // LDS tile row stride: 1072 B/row -> 16 B aligned rows
                        // (global_load_lds dwordx4 needs 16B LDS alignment);
                        // 268 dw = 12 mod 32 -> worst 2-way banks (free, m136)
#define TSF 532         // fallback path keeps its proven 532 stride

typedef __bf16 bf16x8 __attribute__((ext_vector_type(8)));
typedef __bf16 bf16x4 __attribute__((ext_vector_type(4)));
typedef __bf16 bf16x8a __attribute__((ext_vector_type(8), aligned(8)));
typedef __bf16 bf16x4a __attribute__((ext_vector_type(4), aligned(4)));
typedef float  f32x4  __attribute__((ext_vector_type(4)));

// direct global->LDS, 16 B per lane (one instr moves 1 KB per wave)
#define GLOAD_LDS16(gp, lp)                                                       \
    __builtin_amdgcn_global_load_lds(                                             \
        (const __attribute__((address_space(1))) void*)(gp),                      \
        (__attribute__((address_space(3))) void*)(lp), 16, 0, 0)

// =====================================================================
// K1 (fused): degrees + row-major bf16 apk + xpk + thpk, one adj sweep.
// Blocks 0..751: (b, sub) owns 16 adj rows. Each block:
//   - streams its rows (f32, coalesced), accumulates row sums,
//   - writes the bf16 copy (rows>=NN and cols>=NN zero-filled),
//   - computes dis for its rows, exchanges via LDS,
//   - emits its HALF of xpk tile kc=sub>>1 (xpk tile = 32 k-rows = 2 blocks;
//     half = sub&1 selects quads q<2 / q>=2, i.e. k-local [0,16)/[16,32)).
// Block 752: zeroes xpk tiles kc=94,95 (k padding). Block 753: packs thpk.
// =====================================================================
__global__ __launch_bounds__(256) void k_p1(const float* __restrict__ adj,
                                            const float* __restrict__ x,
                                            const float* __restrict__ theta,
                                            float* __restrict__ dis,
                                            __bf16* __restrict__ apk,
                                            __bf16* __restrict__ xpk,
                                            __bf16* __restrict__ thpk) {
    const int blk = blockIdx.x;
    const int t = threadIdx.x, w = t >> 6, l = t & 63;
    __shared__ float sdis[16];

    if (blk < NIT * BB) {
        const int b = blk / NIT, sub = blk - b * NIT;
        const int i0 = sub * 16;
        // wave w handles rows i0 + w*4 .. +4 (sequential 12 KB streams)
        for (int rr = 0; rr < 4; ++rr) {
            int i = i0 + w * 4 + rr;
            const bool rv = i < NN;
            const float4* row4 = (const float4*)(adj + ((size_t)b * NN + i) * NN);
            __bf16* prow = apk + ((size_t)b * NR + i) * NC;
            float s = 0.f;
            for (int c = l; c < 768; c += 64) {     // 750 live float4 + zero pad
                float4 v = {0.f, 0.f, 0.f, 0.f};
                if (rv && c < 750) v = row4[c];
                s += (v.x + v.y) + (v.z + v.w);
                bf16x4a o;
                o[0] = (__bf16)v.x; o[1] = (__bf16)v.y;
                o[2] = (__bf16)v.z; o[3] = (__bf16)v.w;
                *(bf16x4a*)(prow + c * 4) = o;
            }
            for (int off = 32; off > 0; off >>= 1) s += __shfl_down(s, off, 64);
            if (l == 0) {
                float d = 1.0f / sqrtf(s + 1.0f);
                sdis[w * 4 + rr] = d;
                if (rv) dis[b * NN + i] = d;
            }
        }
        __syncthreads();
        // ---- xpk half-tile: kc = sub>>1, this block covers its 16 k-rows
        const int kc = sub >> 1, half = sub & 1;
        const int m = l & 15, q = l >> 4;
        if ((q >> 1) == half) {
            #pragma unroll
            for (int h = 0; h < 2; ++h) {
                int nt = w + h * 4;
                int f  = nt * 16 + m;
                bf16x8 v;
                #pragma unroll
                for (int j = 0; j < 8; ++j) {
                    int k = kc * 32 + q * 8 + j;        // within [i0, i0+16)
                    float val = 0.f;
                    if (k < NN) val = sdis[q * 8 + j - half * 16] *
                                      x[((size_t)b * NN + k) * FF + f];
                    v[j] = (__bf16)val;
                }
                *(bf16x8*)(xpk + ((size_t)(b * 8 + nt) * NKC + kc) * 512 + l * 8) = v;
            }
        }
    } else if (blk == NIT * BB) {
        // zero xpk tiles kc=94,95 for all (b,nt): 32 tiles x 2 kc x 512 bf16
        for (int idx = t; idx < 4096; idx += 256) {
            int l8   = idx & 63;
            int tile = idx >> 6;                 // (b*8+nt)*2 + kc2
            int kc   = 94 + (tile & 1);
            int bnt  = tile >> 1;
            bf16x8 z = {(__bf16)0.f, (__bf16)0.f, (__bf16)0.f, (__bf16)0.f,
                        (__bf16)0.f, (__bf16)0.f, (__bf16)0.f, (__bf16)0.f};
            *(bf16x8*)(xpk + ((size_t)bnt * NKC + kc) * 512 + l8 * 8) = z;
        }
    } else {
        // thpk pack (blk == NIT*BB+1)
        const int m = l & 15, q = l >> 4;
        for (int kc = 0; kc < 4; ++kc) {
            #pragma unroll
            for (int h = 0; h < 2; ++h) {
                int nt = w + h * 4;
                bf16x8 v;
                #pragma unroll
                for (int j = 0; j < 8; ++j) {
                    int k = kc * 32 + q * 8 + j;
                    v[j] = (__bf16)theta[k * FF + nt * 16 + m];
                }
                *(bf16x8*)(thpk + ((size_t)(nt * 4 + kc)) * 512 + l * 8) = v;
            }
        }
    }
}

// =====================================================================
// K3: LDS-staged MFMA with DIRECT global_load_lds A-staging (16 B/lane).
// TS=536 keeps every row base 16 B-aligned for the LDS-direct writes.
// =====================================================================
__global__ __launch_bounds__(256) void k_agg4(const __bf16* __restrict__ apk,
                                              const __bf16* __restrict__ xpk,
                                              const __bf16* __restrict__ thpk,
                                              const float* __restrict__ x,
                                              const float* __restrict__ h0,
                                              const float* __restrict__ dis,
                                              float* __restrict__ out,
                                              const float* __restrict__ alpha_p,
                                              const float* __restrict__ lamda_p,
                                              const int* __restrict__ l_p) {
    __shared__ __bf16 tile[2][16][TS];
    __shared__ __bf16 stile[16][140];
    const int id = blockIdx.x;
    const int b  = (id >> 1) & 3;                 // XCD pair per batch (L2 locality)
    const int it = (id >> 3) * 2 + (id & 1);
    const int i0 = it * 16;
    const int t  = threadIdx.x, w = t >> 6, l = t & 63;
    const int m  = l & 15, quad = l >> 4;
    const int n0 = w * 32;
    const __bf16* Abase = apk + ((size_t)b * NR + i0) * NC;   // 16 padded rows
    const __bf16* B0 = xpk + ((size_t)(b * 8 + 2 * w) * NKC) * 512 + l * 8;
    const __bf16* B1 = B0 + (size_t)NKC * 512;
    f32x4 acc0 = {0.f, 0.f, 0.f, 0.f};
    f32x4 acc1 = {0.f, 0.f, 0.f, 0.f};

    // wave w stages rows {w, 4+w, 8+w, 12+w}; one 1 KB instr per row-chunk
    auto stage_chunk = [&](int c, int cb) {
        #pragma unroll
        for (int i = 0; i < 4; ++i) {
            int row = i * 4 + w;
            GLOAD_LDS16(Abase + (size_t)row * NC + c * 512 + l * 8,
                        &tile[cb][row][0]);
        }
    };

    stage_chunk(0, 0);
    __syncthreads();                               // drains vmcnt -> buf 0 ready
    for (int c = 0; c < 6; ++c) {
        int cb = c & 1;
        if (c < 5) stage_chunk(c + 1, cb ^ 1);     // async into other buffer
        #pragma unroll 4
        for (int kcl = 0; kcl < 16; ++kcl) {
            int kc = c * 16 + kcl;
            bf16x8 a  = *(const bf16x8a*)&tile[cb][m][kcl * 32 + quad * 8];
            bf16x8 b0 = *(const bf16x8*)(B0 + (size_t)kc * 512);
            bf16x8 b1 = *(const bf16x8*)(B1 + (size_t)kc * 512);
            acc0 = __builtin_amdgcn_mfma_f32_16x16x32_bf16(a, b0, acc0, 0, 0, 0);
            acc1 = __builtin_amdgcn_mfma_f32_16x16x32_bf16(a, b1, acc1, 0, 0, 0);
        }
        __syncthreads();                           // waits prefetch + ds reads
    }

    // ---- epilogue: support values; stage tile in A-layout (bf16) ----
    const float alpha = *alpha_p;
    const float beta  = logf(*lamda_p / (float)(*l_p) + 1.0f);
    float s0v[4], s1v[4];
    #pragma unroll
    for (int r = 0; r < 4; ++r) {
        int row  = quad * 4 + r;
        int irow = i0 + row;
        float s0 = 0.f, s1 = 0.f;
        if (irow < NN) {
            float  di   = dis[b * NN + irow];
            size_t base = ((size_t)b * NN + irow) * FF;
            int c0 = n0 + m, c1 = n0 + 16 + m;
            s0 = (1.f - alpha) * (di * acc0[r] + di * di * x[base + c0]) + alpha * h0[base + c0];
            s1 = (1.f - alpha) * (di * acc1[r] + di * di * x[base + c1]) + alpha * h0[base + c1];
        }
        s0v[r] = s0; s1v[r] = s1;
        stile[row][n0 + m]      = (__bf16)s0;
        stile[row][n0 + 16 + m] = (__bf16)s1;
    }
    __syncthreads();
    // ---- theta matmul on the 16x128 support tile ----
    f32x4 o0 = {0.f, 0.f, 0.f, 0.f};
    f32x4 o1 = {0.f, 0.f, 0.f, 0.f};
    const __bf16* T0 = thpk + (size_t)(2 * w * 4) * 512 + l * 8;
    const __bf16* T1 = T0 + 4 * 512;
    #pragma unroll
    for (int kc = 0; kc < 4; ++kc) {
        bf16x4a alo = *(const bf16x4a*)&stile[m][kc * 32 + quad * 8];
        bf16x4a ahi = *(const bf16x4a*)&stile[m][kc * 32 + quad * 8 + 4];
        bf16x8 a = __builtin_shufflevector(alo, ahi, 0, 1, 2, 3, 4, 5, 6, 7);
        bf16x8 tb0 = *(const bf16x8*)(T0 + (size_t)kc * 512);
        bf16x8 tb1 = *(const bf16x8*)(T1 + (size_t)kc * 512);
        o0 = __builtin_amdgcn_mfma_f32_16x16x32_bf16(a, tb0, o0, 0, 0, 0);
        o1 = __builtin_amdgcn_mfma_f32_16x16x32_bf16(a, tb1, o1, 0, 0, 0);
    }
    const float omb = 1.f - beta;
    #pragma unroll
    for (int r = 0; r < 4; ++r) {
        int irow = i0 + quad * 4 + r;
        if (irow < NN) {
            size_t base = ((size_t)b * NN + irow) * FF;
            out[base + n0 + m]      = beta * o0[r] + omb * s0v[r];
            out[base + n0 + 16 + m] = beta * o1[r] + omb * s1v[r];
        }
    }
}

// =====================================================================
// FALLBACK (only if workspace too small) — original 275 us path, unchanged
// =====================================================================
__global__ __launch_bounds__(256) void k_deg(const float* __restrict__ adj,
                                             float* __restrict__ dis) {
    int wid  = (blockIdx.x * 256 + threadIdx.x) >> 6;
    int lane = threadIdx.x & 63;
    if (wid >= BB * NN) return;
    const float4* row = (const float4*)(adj + (size_t)wid * NN);
    float s = 0.f;
    for (int c = lane; c < NN / 4; c += 64) {
        float4 v = row[c];
        s += (v.x + v.y) + (v.z + v.w);
    }
    for (int off = 32; off > 0; off >>= 1) s += __shfl_down(s, off, 64);
    if (lane == 0) dis[wid] = 1.0f / sqrtf(s + 1.0f);
}

__global__ __launch_bounds__(256) void k_agg(const float* __restrict__ adj,
                                             const __bf16* __restrict__ xpk,
                                             const __bf16* __restrict__ thpk,
                                             const float* __restrict__ x,
                                             const float* __restrict__ h0,
                                             const float* __restrict__ dis,
                                             float* __restrict__ out,
                                             const float* __restrict__ alpha_p,
                                             const float* __restrict__ lamda_p,
                                             const int* __restrict__ l_p) {
    __shared__ __bf16 tile[2][16][TSF];
    __shared__ __bf16 stile[16][140];
    const int id = blockIdx.x;
    const int b  = (id >> 1) & 3;
    const int it = (id >> 3) * 2 + (id & 1);
    const int i0 = it * 16;
    const int t  = threadIdx.x, w = t >> 6, l = t & 63;
    const int m  = l & 15, quad = l >> 4;
    const int n0 = w * 32;
    const __bf16* B0 = xpk + ((size_t)(b * 8 + 2 * w) * NKC) * 512 + l * 8;
    const __bf16* B1 = B0 + (size_t)NKC * 512;
    f32x4 acc0 = {0.f, 0.f, 0.f, 0.f};
    f32x4 acc1 = {0.f, 0.f, 0.f, 0.f};

    float4 pu[4], pv[4];
    auto load_chunk = [&](int c) {
        #pragma unroll
        for (int i = 0; i < 4; ++i) {
            int row  = i * 4 + w;
            int irow = i0 + row;
            int col  = c * 512 + l * 8;
            float4 u = {0.f, 0.f, 0.f, 0.f}, v = {0.f, 0.f, 0.f, 0.f};
            if (irow < NN && col < NN) {
                const float* p = adj + ((size_t)b * NN + irow) * NN + col;
                u = *(const float4*)p;
                v = *(const float4*)(p + 4);
            }
            pu[i] = u; pv[i] = v;
        }
    };
    auto store_chunk = [&](int cb) {
        #pragma unroll
        for (int i = 0; i < 4; ++i) {
            int row = i * 4 + w;
            bf16x8a s;
            s[0] = (__bf16)pu[i].x; s[1] = (__bf16)pu[i].y;
            s[2] = (__bf16)pu[i].z; s[3] = (__bf16)pu[i].w;
            s[4] = (__bf16)pv[i].x; s[5] = (__bf16)pv[i].y;
            s[6] = (__bf16)pv[i].z; s[7] = (__bf16)pv[i].w;
            *(bf16x8a*)&tile[cb][row][l * 8] = s;
        }
    };

    load_chunk(0);
    store_chunk(0);
    __syncthreads();
    for (int c = 0; c < 6; ++c) {
        int cb = c & 1;
        if (c < 5) load_chunk(c + 1);
        #pragma unroll 4
        for (int kcl = 0; kcl < 16; ++kcl) {
            int kc = c * 16 + kcl;
            bf16x8 a = *(const bf16x8a*)&tile[cb][m][kcl * 32 + quad * 8];
            bf16x8 b0 = *(const bf16x8*)(B0 + (size_t)kc * 512);
            bf16x8 b1 = *(const bf16x8*)(B1 + (size_t)kc * 512);
            acc0 = __builtin_amdgcn_mfma_f32_16x16x32_bf16(a, b0, acc0, 0, 0, 0);
            acc1 = __builtin_amdgcn_mfma_f32_16x16x32_bf16(a, b1, acc1, 0, 0, 0);
        }
        if (c < 5) store_chunk(cb ^ 1);
        __syncthreads();
    }

    const float alpha = *alpha_p;
    const float beta  = logf(*lamda_p / (float)(*l_p) + 1.0f);
    float s0v[4], s1v[4];
    #pragma unroll
    for (int r = 0; r < 4; ++r) {
        int row  = quad * 4 + r;
        int irow = i0 + row;
        float s0 = 0.f, s1 = 0.f;
        if (irow < NN) {
            float  di   = dis[b * NN + irow];
            size_t base = ((size_t)b * NN + irow) * FF;
            int c0 = n0 + m, c1 = n0 + 16 + m;
            s0 = (1.f - alpha) * (di * acc0[r] + di * di * x[base + c0]) + alpha * h0[base + c0];
            s1 = (1.f - alpha) * (di * acc1[r] + di * di * x[base + c1]) + alpha * h0[base + c1];
        }
        s0v[r] = s0; s1v[r] = s1;
        stile[row][n0 + m]      = (__bf16)s0;
        stile[row][n0 + 16 + m] = (__bf16)s1;
    }
    __syncthreads();
    f32x4 o0 = {0.f, 0.f, 0.f, 0.f};
    f32x4 o1 = {0.f, 0.f, 0.f, 0.f};
    const __bf16* T0 = thpk + (size_t)(2 * w * 4) * 512 + l * 8;
    const __bf16* T1 = T0 + 4 * 512;
    #pragma unroll
    for (int kc = 0; kc < 4; ++kc) {
        bf16x4a alo = *(const bf16x4a*)&stile[m][kc * 32 + quad * 8];
        bf16x4a ahi = *(const bf16x4a*)&stile[m][kc * 32 + quad * 8 + 4];
        bf16x8 a = __builtin_shufflevector(alo, ahi, 0, 1, 2, 3, 4, 5, 6, 7);
        bf16x8 tb0 = *(const bf16x8*)(T0 + (size_t)kc * 512);
        bf16x8 tb1 = *(const bf16x8*)(T1 + (size_t)kc * 512);
        o0 = __builtin_amdgcn_mfma_f32_16x16x32_bf16(a, tb0, o0, 0, 0, 0);
        o1 = __builtin_amdgcn_mfma_f32_16x16x32_bf16(a, tb1, o1, 0, 0, 0);
    }
    const float omb = 1.f - beta;
    #pragma unroll
    for (int r = 0; r < 4; ++r) {
        int irow = i0 + quad * 4 + r;
        if (irow < NN) {
            size_t base = ((size_t)b * NN + irow) * FF;
            out[base + n0 + m]      = beta * o0[r] + omb * s0v[r];
            out[base + n0 + 16 + m] = beta * o1[r] + omb * s1v[r];
        }
    }
}

__global__ __launch_bounds__(256) void k_thpk_fb(const float* __restrict__ theta,
                                                 __bf16* __restrict__ thpk) {
    int kc = blockIdx.x;
    int t  = threadIdx.x, w = t >> 6, l = t & 63;
    int m  = l & 15, q = l >> 4;
    #pragma unroll
    for (int h = 0; h < 2; ++h) {
        int nt = w + h * 4;
        bf16x8 v;
        #pragma unroll
        for (int j = 0; j < 8; ++j) {
            int k = kc * 32 + q * 8 + j;
            v[j] = (__bf16)theta[k * FF + nt * 16 + m];
        }
        *(bf16x8*)(thpk + ((size_t)(nt * 4 + kc)) * 512 + l * 8) = v;
    }
}

__global__ __launch_bounds__(256) void k_xpk_fb(const float* __restrict__ x,
                                                const float* __restrict__ dis,
                                                __bf16* __restrict__ xpk) {
    int b  = blockIdx.y, kc = blockIdx.x;
    int t  = threadIdx.x, w = t >> 6, l = t & 63;
    int m  = l & 15, q = l >> 4;
    #pragma unroll
    for (int h = 0; h < 2; ++h) {
        int nt = w + h * 4;
        int f  = nt * 16 + m;
        bf16x8 v;
        #pragma unroll
        for (int j = 0; j < 8; ++j) {
            int k = kc * 32 + q * 8 + j;
            float val = 0.f;
            if (k < NN) val = dis[b * NN + k] * x[((size_t)b * NN + k) * FF + f];
            v[j] = (__bf16)val;
        }
        *(bf16x8*)(xpk + ((size_t)(b * 8 + nt) * NKC + kc) * 512 + l * 8) = v;
    }
}

// =====================================================================

extern "C" void kernel_launch(void* const* d_in, const int* in_sizes, int n_in,
                              void* d_out, int out_size, void* d_ws, size_t ws_size,
                              hipStream_t stream) {
    const float* x      = (const float*)d_in[0];
    const float* adj    = (const float*)d_in[1];
    const float* h0     = (const float*)d_in[2];
    const float* theta  = (const float*)d_in[3];
    const float* lamda  = (const float*)d_in[4];
    const float* alpha  = (const float*)d_in[5];
    const int*   l      = (const int*)d_in[6];
    float* out = (float*)d_out;

    char* ws = (char*)d_ws;

    // workspace: dis 48,000 | thpk 32,768 | xpk 3,145,728 | apk 73,924,608
    const size_t APK_OFF = 3276800;                                     // 1K-aligned
    const size_t WS_NEED = APK_OFF + (size_t)BB * NR * NC * 2;          // 77,201,408

    if (ws_size >= WS_NEED) {
        float*  dis  = (float*)ws;
        __bf16* thpk = (__bf16*)(ws + 65536);
        __bf16* xpk  = (__bf16*)(ws + 131072);
        __bf16* apk  = (__bf16*)(ws + APK_OFF);

        k_p1<<<dim3(NIT * BB + 2), 256, 0, stream>>>(adj, x, theta, dis, apk, xpk, thpk);
        k_agg4<<<dim3(NIT * BB), 256, 0, stream>>>(apk, xpk, thpk, x, h0, dis, out,
                                                   alpha, lamda, l);
    } else {
        float*  dis  = (float*)ws;
        __bf16* xpk  = (__bf16*)(ws + 65536);
        __bf16* thpk = (__bf16*)(ws + 3276800);

        k_deg<<<dim3((BB * NN) / 4), 256, 0, stream>>>(adj, dis);
        k_thpk_fb<<<dim3(4), 256, 0, stream>>>(theta, thpk);
        k_xpk_fb<<<dim3(NKC, BB), 256, 0, stream>>>(x, dis, xpk);
        k_agg<<<dim3(NIT * BB), 256, 0, stream>>>(adj, xpk, thpk, x, h0, dis, out,
                                                  alpha, lamda, l);
    }
}

// Round 6
// 276.505 us; speedup vs baseline: 1.0189x; 1.0189x over previous
//
#include <hip/hip_runtime.h>
#include <hip/hip_bf16.h>
#include <math.h>

#define BB 4
#define NN 3000
#define FF 128
#define NKC 96          // 32-wide K chunks (96*32 = 3072), 6 big chunks x 16
#define NIT 188         // 16-row tiles (188*16 = 3008)
#define TS  532         // LDS tile row stride: 266 dw = 10 mod 32 -> <=2-way banks

typedef __bf16 bf16x8 __attribute__((ext_vector_type(8)));
typedef __bf16 bf16x4 __attribute__((ext_vector_type(4)));
typedef __bf16 bf16x8a __attribute__((ext_vector_type(8), aligned(8)));
typedef __bf16 bf16x4a __attribute__((ext_vector_type(4), aligned(4)));
typedef float  f32x4  __attribute__((ext_vector_type(4)));

// ---------------- K1: dis[b*NN+i] = 1/sqrt(1 + sum_j adj[b,i,j]) ----------------
__global__ __launch_bounds__(256) void k_deg(const float* __restrict__ adj,
                                             float* __restrict__ dis) {
    int wid  = (blockIdx.x * 256 + threadIdx.x) >> 6;
    int lane = threadIdx.x & 63;
    if (wid >= BB * NN) return;
    const float4* row = (const float4*)(adj + (size_t)wid * NN);
    float s = 0.f;
    for (int c = lane; c < NN / 4; c += 64) {
        float4 v = row[c];
        s += (v.x + v.y) + (v.z + v.w);
    }
    for (int off = 32; off > 0; off >>= 1) s += __shfl_down(s, off, 64);
    if (lane == 0) dis[wid] = 1.0f / sqrtf(s + 1.0f);
}

// ---------------- K2: pack xs = dis_k * x[k][f] into MFMA B-fragment order ------
__global__ __launch_bounds__(256) void k_xpk(const float* __restrict__ x,
                                             const float* __restrict__ dis,
                                             __bf16* __restrict__ xpk) {
    int b  = blockIdx.y, kc = blockIdx.x;
    int t  = threadIdx.x, w = t >> 6, l = t & 63;
    int m  = l & 15, q = l >> 4;
    #pragma unroll
    for (int h = 0; h < 2; ++h) {
        int nt = w + h * 4;
        int f  = nt * 16 + m;
        bf16x8 v;
        #pragma unroll
        for (int j = 0; j < 8; ++j) {
            int k = kc * 32 + q * 8 + j;
            float val = 0.f;
            if (k < NN) val = dis[b * NN + k] * x[((size_t)b * NN + k) * FF + f];
            v[j] = (__bf16)val;
        }
        *(bf16x8*)(xpk + ((size_t)(b * 8 + nt) * NKC + kc) * 512 + l * 8) = v;
    }
}

// ---------------- K2b: pack theta into MFMA B-fragment order --------------------
__global__ __launch_bounds__(256) void k_thpk(const float* __restrict__ theta,
                                              __bf16* __restrict__ thpk) {
    int kc = blockIdx.x;
    int t  = threadIdx.x, w = t >> 6, l = t & 63;
    int m  = l & 15, q = l >> 4;
    #pragma unroll
    for (int h = 0; h < 2; ++h) {
        int nt = w + h * 4;
        bf16x8 v;
        #pragma unroll
        for (int j = 0; j < 8; ++j) {
            int k = kc * 32 + q * 8 + j;
            v[j] = (__bf16)theta[k * FF + nt * 16 + m];
        }
        *(bf16x8*)(thpk + ((size_t)(nt * 4 + kc)) * 512 + l * 8) = v;
    }
}

// ---------------- K3 (fused): out = beta*(support@theta) + (1-beta)*support ------
// Best-measured configuration (275.2 us): dbuf BK=512, 1 barrier/chunk,
// LDS tile stride 532 (<=2-way banks), 1-D grid + XCD swizzle (batch b pinned
// to XCDs {2b,2b+1} so each XCD's L2 holds one 3 MB xpk slice).
__global__ __launch_bounds__(256) void k_agg(const float* __restrict__ adj,
                                             const __bf16* __restrict__ xpk,
                                             const __bf16* __restrict__ thpk,
                                             const float* __restrict__ x,
                                             const float* __restrict__ h0,
                                             const float* __restrict__ dis,
                                             float* __restrict__ out,
                                             const float* __restrict__ alpha_p,
                                             const float* __restrict__ lamda_p,
                                             const int* __restrict__ l_p) {
    __shared__ __bf16 tile[2][16][TS];
    __shared__ __bf16 stile[16][140];
    const int id = blockIdx.x;
    const int b  = (id >> 1) & 3;                 // XCD pair per batch
    const int it = (id >> 3) * 2 + (id & 1);
    const int i0 = it * 16;
    const int t  = threadIdx.x, w = t >> 6, l = t & 63;
    const int m  = l & 15, quad = l >> 4;
    const int n0 = w * 32;
    const __bf16* B0 = xpk + ((size_t)(b * 8 + 2 * w) * NKC) * 512 + l * 8;
    const __bf16* B1 = B0 + (size_t)NKC * 512;
    f32x4 acc0 = {0.f, 0.f, 0.f, 0.f};
    f32x4 acc1 = {0.f, 0.f, 0.f, 0.f};

    float4 pu[4], pv[4];
    // wave w stages rows {w, 4+w, 8+w, 12+w}; lane l covers cols [l*8, l*8+8)
    auto load_chunk = [&](int c) {
        #pragma unroll
        for (int i = 0; i < 4; ++i) {
            int row  = i * 4 + w;
            int irow = i0 + row;
            int col  = c * 512 + l * 8;
            float4 u = {0.f, 0.f, 0.f, 0.f}, v = {0.f, 0.f, 0.f, 0.f};
            if (irow < NN && col < NN) {   // NN%8==0
                const float* p = adj + ((size_t)b * NN + irow) * NN + col;
                u = *(const float4*)p;
                v = *(const float4*)(p + 4);
            }
            pu[i] = u; pv[i] = v;
        }
    };
    auto store_chunk = [&](int cb) {
        #pragma unroll
        for (int i = 0; i < 4; ++i) {
            int row = i * 4 + w;
            bf16x8a s;
            s[0] = (__bf16)pu[i].x; s[1] = (__bf16)pu[i].y;
            s[2] = (__bf16)pu[i].z; s[3] = (__bf16)pu[i].w;
            s[4] = (__bf16)pv[i].x; s[5] = (__bf16)pv[i].y;
            s[6] = (__bf16)pv[i].z; s[7] = (__bf16)pv[i].w;
            *(bf16x8a*)&tile[cb][row][l * 8] = s;
        }
    };

    load_chunk(0);
    store_chunk(0);
    __syncthreads();
    for (int c = 0; c < 6; ++c) {
        int cb = c & 1;
        if (c < 5) load_chunk(c + 1);
        #pragma unroll 4
        for (int kcl = 0; kcl < 16; ++kcl) {
            int kc = c * 16 + kcl;
            bf16x8 a = *(const bf16x8a*)&tile[cb][m][kcl * 32 + quad * 8];
            bf16x8 b0 = *(const bf16x8*)(B0 + (size_t)kc * 512);
            bf16x8 b1 = *(const bf16x8*)(B1 + (size_t)kc * 512);
            acc0 = __builtin_amdgcn_mfma_f32_16x16x32_bf16(a, b0, acc0, 0, 0, 0);
            acc1 = __builtin_amdgcn_mfma_f32_16x16x32_bf16(a, b1, acc1, 0, 0, 0);
        }
        if (c < 5) store_chunk(cb ^ 1);
        __syncthreads();
    }

    // ---- epilogue: support values; stage tile in A-layout (bf16) ----
    const float alpha = *alpha_p;
    const float beta  = logf(*lamda_p / (float)(*l_p) + 1.0f);
    float s0v[4], s1v[4];
    #pragma unroll
    for (int r = 0; r < 4; ++r) {
        int row  = quad * 4 + r;
        int irow = i0 + row;
        float s0 = 0.f, s1 = 0.f;
        if (irow < NN) {
            float  di   = dis[b * NN + irow];
            size_t base = ((size_t)b * NN + irow) * FF;
            int c0 = n0 + m, c1 = n0 + 16 + m;
            s0 = (1.f - alpha) * (di * acc0[r] + di * di * x[base + c0]) + alpha * h0[base + c0];
            s1 = (1.f - alpha) * (di * acc1[r] + di * di * x[base + c1]) + alpha * h0[base + c1];
        }
        s0v[r] = s0; s1v[r] = s1;
        stile[row][n0 + m]      = (__bf16)s0;
        stile[row][n0 + 16 + m] = (__bf16)s1;
    }
    __syncthreads();
    // ---- theta matmul on the 16x128 support tile ----
    f32x4 o0 = {0.f, 0.f, 0.f, 0.f};
    f32x4 o1 = {0.f, 0.f, 0.f, 0.f};
    const __bf16* T0 = thpk + (size_t)(2 * w * 4) * 512 + l * 8;
    const __bf16* T1 = T0 + 4 * 512;
    #pragma unroll
    for (int kc = 0; kc < 4; ++kc) {
        bf16x4a alo = *(const bf16x4a*)&stile[m][kc * 32 + quad * 8];
        bf16x4a ahi = *(const bf16x4a*)&stile[m][kc * 32 + quad * 8 + 4];
        bf16x8 a = __builtin_shufflevector(alo, ahi, 0, 1, 2, 3, 4, 5, 6, 7);
        bf16x8 tb0 = *(const bf16x8*)(T0 + (size_t)kc * 512);
        bf16x8 tb1 = *(const bf16x8*)(T1 + (size_t)kc * 512);
        o0 = __builtin_amdgcn_mfma_f32_16x16x32_bf16(a, tb0, o0, 0, 0, 0);
        o1 = __builtin_amdgcn_mfma_f32_16x16x32_bf16(a, tb1, o1, 0, 0, 0);
    }
    const float omb = 1.f - beta;
    #pragma unroll
    for (int r = 0; r < 4; ++r) {
        int irow = i0 + quad * 4 + r;
        if (irow < NN) {
            size_t base = ((size_t)b * NN + irow) * FF;
            out[base + n0 + m]      = beta * o0[r] + omb * s0v[r];
            out[base + n0 + 16 + m] = beta * o1[r] + omb * s1v[r];
        }
    }
}

extern "C" void kernel_launch(void* const* d_in, const int* in_sizes, int n_in,
                              void* d_out, int out_size, void* d_ws, size_t ws_size,
                              hipStream_t stream) {
    const float* x      = (const float*)d_in[0];
    const float* adj    = (const float*)d_in[1];
    const float* h0     = (const float*)d_in[2];
    const float* theta  = (const float*)d_in[3];
    const float* lamda  = (const float*)d_in[4];
    const float* alpha  = (const float*)d_in[5];
    const int*   l      = (const int*)d_in[6];
    float* out = (float*)d_out;

    char*   ws   = (char*)d_ws;
    float*  dis  = (float*)ws;                 // 48,000 B
    __bf16* xpk  = (__bf16*)(ws + 65536);      // 4*8*96*512*2 = 3,145,728 B
    __bf16* thpk = (__bf16*)(ws + 3276800);    // 32,768 B

    k_deg<<<dim3((BB * NN) / 4), 256, 0, stream>>>(adj, dis);
    k_thpk<<<dim3(4), 256, 0, stream>>>(theta, thpk);
    k_xpk<<<dim3(NKC, BB), 256, 0, stream>>>(x, dis, xpk);
    k_agg<<<dim3(NIT * BB), 256, 0, stream>>>(adj, xpk, thpk, x, h0, dis, out,
                                              alpha, lamda, l);
}